// Round 8
// baseline (1436.404 us; speedup 1.0000x reference)
//
#include <hip/hip_runtime.h>

#define NN 32768      // total nodes
#define NP 512        // nodes per graph
#define NB 64         // graphs
#define NE 1048576    // edges
#define FIN 16
#define H 128
#define BN_EPS 1e-5f
#define EPB 4096      // edges per hist/scatter chunk
#define NBLK (NE / EPB)   // 256
#define CAPQ 4608     // max edges per dst-quarter of a graph
#define NSH 32        // BN shadow copies
#define GRID 512
#define NTHR 256

typedef unsigned int u32;
typedef unsigned short u16;
typedef __attribute__((ext_vector_type(8))) short bf16x8;
typedef __attribute__((ext_vector_type(4))) float f32x4;

__device__ __forceinline__ u16 f2bf(float f) {
    u32 u = __float_as_uint(f);
    return (u16)((u + 0x7fffu + ((u >> 16) & 1u)) >> 16);
}
__device__ __forceinline__ float bfLo(u32 p) { return __uint_as_float(p << 16); }
__device__ __forceinline__ float bfHi(u32 p) { return __uint_as_float(p & 0xffff0000u); }

// ---------------- workspace layout (bytes) ----------------
static constexpr size_t SZ_HALF   = (size_t)NN * H * 2;            // 8 MiB
static constexpr size_t OFF_X     = 0;
static constexpr size_t OFF_Y     = OFF_X + SZ_HALF;
static constexpr size_t OFF_AGG   = OFF_Y + SZ_HALF;               // aliases TMP
static constexpr size_t OFF_TMP   = OFF_AGG;
static constexpr size_t OFF_SORT  = OFF_AGG + SZ_HALF;
static constexpr size_t OFF_OFFS  = OFF_SORT + (size_t)NE * 8;     // NN+8 ints
static constexpr size_t OFF_HISTG = OFF_OFFS + ((size_t)NN + 128) * 4;
static constexpr size_t OFF_STARTG= OFF_HISTG + (size_t)NBLK * NB * 4;
static constexpr size_t OFF_GBASE = OFF_STARTG + (size_t)NBLK * NB * 4;  // 65 ints
static constexpr size_t OFF_WT1   = OFF_GBASE + 512;               // 64 KiB
static constexpr size_t OFF_WT2   = OFF_WT1 + (size_t)H * 2 * H * 2;
static constexpr size_t OFF_S     = OFF_WT2 + (size_t)H * 2 * H * 2;   // NN*2 f32
static constexpr size_t OFF_GST   = OFF_S + (size_t)NN * 2 * 4;
static constexpr size_t OFF_BARS  = OFF_GST + 1024;                // 16*64 u32 = 4 KiB (memset)
// --- zeroed-in-kernel region ---
static constexpr size_t OFF_ZERO  = OFF_BARS + 4096;
static constexpr size_t OFF_NUM   = OFF_ZERO;                      // NB f32
static constexpr size_t OFF_DEN   = OFF_NUM + 256;
static constexpr size_t OFF_BN    = OFF_DEN + 256;                 // 2 * NSH * 2 * H f32
static constexpr size_t SZ_BNL    = (size_t)NSH * 2 * H * 4;
static constexpr size_t OFF_POOL  = OFF_BN + 2 * SZ_BNL;           // NB*2*H f32
static constexpr size_t ZERO_BYTES= (OFF_POOL + (size_t)NB * 2 * H * 4) - OFF_ZERO;
static constexpr int    ZERO_N    = (int)(ZERO_BYTES / 4);

struct KParams {
    const float *nf, *Wpre, *bpre;
    const float *W1rel, *b1rel, *W1root, *g1, *be1;
    const float *W2rel, *b2rel, *W2root, *g2, *be2;
    const float *Wpool, *bpool, *Wpost, *bpost;
    const int *src, *dst; const float *ew;
    u16 *bufX, *bufY, *bufAgg;
    int2 *tmp, *sorted;
    int *offs, *histG, *startG, *gbase;
    u16 *WT1, *WT2;
    float *sarr, *gst, *num, *den, *bn1, *bn2, *pool;
    u32 *zeroP;
    u32 *bars;
    float *out;
};

struct SMem {
    union {
        struct { float sW[FIN * H]; float sNF[16 * FIN]; } pre;
        struct { int h[NB]; } hist;
        struct { int wsum[4]; } scan;
        struct { int part[4][64]; } gb;
        struct { int lstart[NB + 1]; int cursor[NB]; int gdst[NB]; int2 buf[EPB]; } sc;   // 32.8 KB
        struct { int hist[NP]; int start[NP + 1]; int cursor[128]; int wsum[4]; int perm[CAPQ]; } sb;
        struct { u16 sWT[64][264]; float colS[64]; float colQ[64]; } g;                    // 34.3 KB
        struct { float scL[H]; float shL[H]; float poolL[256]; } bn;
        struct { float2 sl[NP]; float ln[4]; float ld[4]; float tp[3][4]; } es;
        struct { float t0[4]; float t1[4]; } lg;
    };
};

// one-shot grid barrier: 64 sub-counters, 8 arrivals each. bars zeroed pre-launch.
__device__ __forceinline__ void gsync(u32* bar) {
    __syncthreads();
    __threadfence();          // release (agent scope): flush my writes
    int t = threadIdx.x;
    if (t == 0)
        __hip_atomic_fetch_add(&bar[blockIdx.x & 63], 1u,
                               __ATOMIC_RELAXED, __HIP_MEMORY_SCOPE_AGENT);
    if (t < 64) {
        int guard = 0;
        while (__hip_atomic_load(&bar[t], __ATOMIC_RELAXED, __HIP_MEMORY_SCOPE_AGENT)
               < (u32)(GRID / 64)) {
            if (++guard > 100000000) break;   // hang guard
        }
    }
    __syncthreads();
    __threadfence();          // acquire: invalidate stale cache lines
}

// ---- gemm phase: Y = [A|X](bf16) @ WT^T + brel, MFMA, fp32 acc, BN partials ----
__device__ __forceinline__ void gemm_phase(SMem& sm, int b, int t,
        const u16* __restrict__ A, const u16* __restrict__ X,
        const u16* __restrict__ WT, const float* __restrict__ brel,
        u16* __restrict__ Y, float* __restrict__ bnb) {
    int w = t >> 6, lane = t & 63, lr = lane & 15, lg = lane >> 4;
    int rowg = w & 1, colg = w >> 1;
    for (int wk = b; wk < 2048; wk += GRID) {
        __syncthreads();
        int row0 = (wk >> 1) * 32, col0 = (wk & 1) * 64;
        for (int i = t; i < 64 * 32; i += NTHR) {
            int r = i >> 5, c = i & 31;
            *(uint4*)&sm.g.sWT[r][c * 8] = *(const uint4*)(WT + (size_t)(col0 + r) * 256 + c * 8);
        }
        if (t < 64) { sm.g.colS[t] = 0.f; sm.g.colQ[t] = 0.f; }
        __syncthreads();
        int myrow = row0 + rowg * 16 + lr;
        bf16x8 af[8];
        const u16* pa = A + (size_t)myrow * H + lg * 8;
        const u16* px = X + (size_t)myrow * H + lg * 8;
        #pragma unroll
        for (int kt = 0; kt < 4; ++kt) {
            af[kt] = *(const bf16x8*)(pa + kt * 32);
            af[4 + kt] = *(const bf16x8*)(px + kt * 32);
        }
        f32x4 a0 = {0.f, 0.f, 0.f, 0.f}, a1 = {0.f, 0.f, 0.f, 0.f};
        #pragma unroll
        for (int kt = 0; kt < 8; ++kt) {
            bf16x8 b0 = *(const bf16x8*)&sm.g.sWT[colg * 32 + lr][kt * 32 + lg * 8];
            bf16x8 b1 = *(const bf16x8*)&sm.g.sWT[colg * 32 + 16 + lr][kt * 32 + lg * 8];
            a0 = __builtin_amdgcn_mfma_f32_16x16x32_bf16(af[kt], b0, a0, 0, 0, 0);
            a1 = __builtin_amdgcn_mfma_f32_16x16x32_bf16(af[kt], b1, a1, 0, 0, 0);
        }
        #pragma unroll
        for (int nt = 0; nt < 2; ++nt) {
            f32x4 ac = nt ? a1 : a0;
            int lcol = colg * 32 + nt * 16 + lr;
            int col = col0 + lcol;
            float bias = brel[col];
            float cs = 0.f, cq = 0.f;
            #pragma unroll
            for (int j = 0; j < 4; ++j) {
                float v = ac[j] + bias;
                int row = row0 + rowg * 16 + lg * 4 + j;
                Y[(size_t)row * H + col] = f2bf(v);
                cs += v; cq += v * v;
            }
            cs += __shfl_xor(cs, 16); cs += __shfl_xor(cs, 32);
            cq += __shfl_xor(cq, 16); cq += __shfl_xor(cq, 32);
            if (lg == 0) {
                atomicAdd(&sm.g.colS[lcol], cs);
                atomicAdd(&sm.g.colQ[lcol], cq);
            }
        }
        __syncthreads();
        if (t < 64) {
            int sh = wk & (NSH - 1);
            atomicAdd(&bnb[(sh * 2 + 0) * H + col0 + t], sm.g.colS[t]);
            atomicAdd(&bnb[(sh * 2 + 1) * H + col0 + t], sm.g.colQ[t]);
        }
    }
}

// ---- agg phase: agg[node,:] = sum_e w_e * x[src_e,:] (L2 gather, XCD-swizzled) ----
__device__ __forceinline__ void agg_phase(int b, int t,
        const u16* __restrict__ x, const int* __restrict__ offs,
        const int2* __restrict__ rec, u16* __restrict__ agg) {
    int wave = t >> 6, lane = t & 63;
    for (int it = 0; it < 16; ++it) {
        int ng = (b & 7) * 1024 + (b >> 3) + it * 64;   // XCD-contiguous
        int node = ng * 4 + wave;
        int sbase = node & ~(NP - 1);
        const u16* xg = x + (size_t)sbase * H;
        int beg = offs[node], end = offs[node + 1];
        float a0 = 0.f, a1 = 0.f;
        int j = beg;
        for (; j + 4 <= end; j += 4) {
            int2 r0 = rec[j], r1 = rec[j + 1], r2 = rec[j + 2], r3 = rec[j + 3];
            u32 p0 = *(const u32*)(xg + (size_t)(r0.x & 511) * H + 2 * lane);
            u32 p1 = *(const u32*)(xg + (size_t)(r1.x & 511) * H + 2 * lane);
            u32 p2 = *(const u32*)(xg + (size_t)(r2.x & 511) * H + 2 * lane);
            u32 p3 = *(const u32*)(xg + (size_t)(r3.x & 511) * H + 2 * lane);
            float w0 = __int_as_float(r0.y), w1 = __int_as_float(r1.y);
            float w2 = __int_as_float(r2.y), w3 = __int_as_float(r3.y);
            a0 += w0 * bfLo(p0); a1 += w0 * bfHi(p0);
            a0 += w1 * bfLo(p1); a1 += w1 * bfHi(p1);
            a0 += w2 * bfLo(p2); a1 += w2 * bfHi(p2);
            a0 += w3 * bfLo(p3); a1 += w3 * bfHi(p3);
        }
        for (; j < end; ++j) {
            int2 r = rec[j];
            u32 p = *(const u32*)(xg + (size_t)(r.x & 511) * H + 2 * lane);
            float w = __int_as_float(r.y);
            a0 += w * bfLo(p); a1 += w * bfHi(p);
        }
        u32 packed = (u32)f2bf(a0) | ((u32)f2bf(a1) << 16);
        *(u32*)(agg + (size_t)node * H + 2 * lane) = packed;
    }
}

// ---- BN finalize + ReLU, in-place on y ----
__device__ __forceinline__ void bnrelu_phase(SMem& sm, int b, int t,
        u16* __restrict__ y, const float* __restrict__ bnb,
        const float* __restrict__ gg, const float* __restrict__ be) {
    __syncthreads();
    if (t < H) {
        float su = 0.f, sq = 0.f;
        #pragma unroll
        for (int sh = 0; sh < NSH; ++sh) {
            su += bnb[(sh * 2 + 0) * H + t];
            sq += bnb[(sh * 2 + 1) * H + t];
        }
        float mu = su * (1.f / NN);
        float var = sq * (1.f / NN) - mu * mu;
        float sc = rsqrtf(var + BN_EPS) * gg[t];
        sm.bn.scL[t] = sc;
        sm.bn.shL[t] = be[t] - mu * sc;
    }
    __syncthreads();
    #pragma unroll
    for (int it = 0; it < 4; ++it) {
        int idx = b * 1024 + it * 256 + t;
        int c = (idx & 15) * 8;
        uint4 u = ((const uint4*)y)[idx];
        u32 uu[4] = {u.x, u.y, u.z, u.w};
        u32 ro[4];
        #pragma unroll
        for (int p = 0; p < 4; ++p) {
            float v0 = fmaxf(fmaf(bfLo(uu[p]), sm.bn.scL[c + 2 * p], sm.bn.shL[c + 2 * p]), 0.f);
            float v1 = fmaxf(fmaf(bfHi(uu[p]), sm.bn.scL[c + 2 * p + 1], sm.bn.shL[c + 2 * p + 1]), 0.f);
            ro[p] = (u32)f2bf(v0) | ((u32)f2bf(v1) << 16);
        }
        uint4 o; o.x = ro[0]; o.y = ro[1]; o.z = ro[2]; o.w = ro[3];
        ((uint4*)y)[idx] = o;
    }
}

__global__ __launch_bounds__(NTHR, 2) void k_mega(KParams P) {
    __shared__ SMem sm;
    int t = threadIdx.x, b = blockIdx.x;
    u32* bar = P.bars;

    // ===== P0: pre-GEMM + WT prep + edge hist + zeroing =====
    for (int wk = b; wk < 2576; wk += GRID) {
        __syncthreads();
        if (wk < 2048) {                       // x0 = nf @ Wpre + bpre (16 nodes)
            for (int i = t; i < FIN * H; i += NTHR) sm.pre.sW[i] = P.Wpre[i];
            int n0 = wk * 16;
            sm.pre.sNF[t] = P.nf[n0 * FIN + t];
            __syncthreads();
            int col = t & 127, half = t >> 7;
            float bb = P.bpre[col];
            #pragma unroll
            for (int r = 0; r < 8; ++r) {
                int rr = half * 8 + r;
                float acc = bb;
                #pragma unroll
                for (int f = 0; f < FIN; ++f)
                    acc += sm.pre.sNF[rr * FIN + f] * sm.pre.sW[f * H + col];
                P.bufX[(size_t)(n0 + rr) * H + col] = f2bf(acc);
            }
        } else if (wk < 2304) {                // WT[c][k] stacked transpose -> bf16
            int base = wk - 2048;
            const float* Wr = (base < 128) ? P.W1rel : P.W2rel;
            const float* Wo = (base < 128) ? P.W1root : P.W2root;
            u16* WT = (base < 128) ? P.WT1 : P.WT2;
            int i = (base & 127) * 256 + t;
            int c = i >> 8, k = i & 255;
            float v = (k < H) ? Wr[k * H + c] : Wo[(k - H) * H + c];
            WT[c * 256 + k] = f2bf(v);
        } else if (wk < 2560) {                // per-chunk graph histogram
            if (t < NB) sm.hist.h[t] = 0;
            __syncthreads();
            int ebase = (wk - 2304) * EPB;
            #pragma unroll
            for (int i = 0; i < EPB / NTHR; ++i) {
                int s = P.src[ebase + i * NTHR + t];
                atomicAdd(&sm.hist.h[s >> 9], 1);
            }
            __syncthreads();
            if (t < NB) P.histG[(wk - 2304) * NB + t] = sm.hist.h[t];
        } else {                               // zero accumulators
            for (int i = (wk - 2560) * NTHR + t; i < ZERO_N; i += 16 * NTHR) P.zeroP[i] = 0;
        }
    }
    gsync(bar); bar += 64;

    // ===== P1: per-graph chunk scans (blocks 0..63) + graph bases (block 64) =====
    if (b < NB) {
        int g = b;
        int v = P.histG[t * NB + g];
        int lane = t & 63, wv = t >> 6;
        int x = v;
        #pragma unroll
        for (int o = 1; o < 64; o <<= 1) { int y = __shfl_up(x, o); if (lane >= o) x += y; }
        if (lane == 63) sm.scan.wsum[wv] = x;
        __syncthreads();
        int off = 0;
        #pragma unroll
        for (int i = 0; i < 4; ++i) off += (i < wv) ? sm.scan.wsum[i] : 0;
        P.startG[t * NB + g] = off + x - v;    // within-graph chunk prefix (no base)
    } else if (b == NB) {
        int g = t & 63, part = t >> 6;
        int s = 0;
        for (int c = part * 64; c < (part + 1) * 64; ++c) s += P.histG[c * NB + g];
        sm.gb.part[part][g] = s;
        __syncthreads();
        if (t < 64) {
            int tot = sm.gb.part[0][t] + sm.gb.part[1][t] + sm.gb.part[2][t] + sm.gb.part[3][t];
            int x = tot;
            #pragma unroll
            for (int o = 1; o < 64; o <<= 1) { int y = __shfl_up(x, o); if (t >= o) x += y; }
            P.gbase[t] = x - tot;
            if (t == 63) P.gbase[64] = x;      // == NE
        }
    }
    gsync(bar); bar += 64;

    // ===== P2: scatter chunks into graph-contiguous tmp =====
    if (b < NBLK) {
        __syncthreads();
        if (t < NB) {
            int c = P.histG[b * NB + t];
            int x = c;
            #pragma unroll
            for (int o = 1; o < 64; o <<= 1) { int y = __shfl_up(x, o); if (t >= o) x += y; }
            sm.sc.lstart[t] = x - c;
            sm.sc.cursor[t] = x - c;
            sm.sc.gdst[t] = P.startG[b * NB + t] + P.gbase[t];
            if (t == 63) sm.sc.lstart[NB] = x;
        }
        __syncthreads();
        int ebase = b * EPB;
        #pragma unroll
        for (int i = 0; i < EPB / NTHR; ++i) {
            int e = ebase + i * NTHR + t;
            int s = P.src[e], d = P.dst[e];
            float w = P.ew[e];
            int g = s >> 9;
            int meta = (s & 511) | ((d & 511) << 9);
            int p = atomicAdd(&sm.sc.cursor[g], 1);
            sm.sc.buf[p] = make_int2(meta, __float_as_int(w));
        }
        __syncthreads();
        for (int i = t; i < EPB; i += NTHR) {
            int lo = 0;
            #pragma unroll
            for (int stp = 32; stp; stp >>= 1)
                if (sm.sc.lstart[lo + stp] <= i) lo += stp;
            P.tmp[sm.sc.gdst[lo] + (i - sm.sc.lstart[lo])] = sm.sc.buf[i];
        }
    }
    gsync(bar); bar += 64;

    // ===== P3: per-graph counting sort by dst (4 quarter-blocks/graph) =====
    if (b < 256) {
        __syncthreads();
        int g = b >> 2, q = b & 3;
        int gbeg = P.gbase[g], gend = P.gbase[g + 1];
        int cnt = gend - gbeg;
        for (int i = t; i < NP; i += NTHR) sm.sb.hist[i] = 0;
        __syncthreads();
        for (int i = t; i < cnt; i += NTHR)
            atomicAdd(&sm.sb.hist[(P.tmp[gbeg + i].x >> 9) & 511], 1);
        __syncthreads();
        int v0 = sm.sb.hist[2 * t], v1 = sm.sb.hist[2 * t + 1];
        int s = v0 + v1;
        int lane = t & 63, wv = t >> 6;
        int x = s;
        #pragma unroll
        for (int o = 1; o < 64; o <<= 1) { int y = __shfl_up(x, o); if (lane >= o) x += y; }
        if (lane == 63) sm.sb.wsum[wv] = x;
        __syncthreads();
        int off = 0;
        #pragma unroll
        for (int i = 0; i < 4; ++i) off += (i < wv) ? sm.sb.wsum[i] : 0;
        int ex = off + x - s;
        sm.sb.start[2 * t] = ex;
        sm.sb.start[2 * t + 1] = ex + v0;
        if (t == 255) sm.sb.start[NP] = ex + s;   // == cnt
        __syncthreads();
        int d0 = q * 128;
        if (t < 128) {
            P.offs[g * NP + d0 + t] = gbeg + sm.sb.start[d0 + t];
            sm.sb.cursor[t] = sm.sb.start[d0 + t];
        }
        if (b == 0 && t == 0) P.offs[NN] = NE;
        __syncthreads();
        int qa = sm.sb.start[d0], qb = sm.sb.start[d0 + 128];
        for (int i = t; i < cnt; i += NTHR) {
            int meta = P.tmp[gbeg + i].x;
            int d = (meta >> 9) & 511;
            if ((d >> 7) == q) {
                int p = atomicAdd(&sm.sb.cursor[d - d0], 1);
                sm.sb.perm[p - qa] = i;
            }
        }
        __syncthreads();
        for (int o = qa + t; o < qb; o += NTHR)
            P.sorted[gbeg + o] = P.tmp[gbeg + sm.sb.perm[o - qa]];
    }
    gsync(bar); bar += 64;

    // ===== layers =====
    agg_phase(b, t, P.bufX, P.offs, P.sorted, P.bufAgg);
    gsync(bar); bar += 64;
    gemm_phase(sm, b, t, P.bufAgg, P.bufX, P.WT1, P.b1rel, P.bufY, P.bn1);
    gsync(bar); bar += 64;
    bnrelu_phase(sm, b, t, P.bufY, P.bn1, P.g1, P.be1);
    gsync(bar); bar += 64;
    agg_phase(b, t, P.bufY, P.offs, P.sorted, P.bufAgg);
    gsync(bar); bar += 64;
    gemm_phase(sm, b, t, P.bufAgg, P.bufY, P.WT2, P.b2rel, P.bufX, P.bn2);
    gsync(bar); bar += 64;

    // ===== P10: BN2 + ReLU + softmax s + pool partials =====
    {
        __syncthreads();
        if (t < H) {
            float su = 0.f, sq = 0.f;
            #pragma unroll
            for (int sh = 0; sh < NSH; ++sh) {
                su += P.bn2[(sh * 2 + 0) * H + t];
                sq += P.bn2[(sh * 2 + 1) * H + t];
            }
            float mu = su * (1.f / NN);
            float var = sq * (1.f / NN) - mu * mu;
            float sc = rsqrtf(var + BN_EPS) * P.g2[t];
            sm.bn.scL[t] = sc;
            sm.bn.shL[t] = P.be2[t] - mu * sc;
        }
        __syncthreads();
        for (int wk = b; wk < 1024; wk += GRID) {
            int graph = wk >> 4, rowbase = (wk & 15) * 32;
            sm.bn.poolL[t] = 0.f;
            __syncthreads();
            int colblk = t & 15;
            int c = colblk * 8;
            float pa0[8], pa1[8];
            #pragma unroll
            for (int j = 0; j < 8; ++j) { pa0[j] = 0.f; pa1[j] = 0.f; }
            #pragma unroll
            for (int it = 0; it < 2; ++it) {
                int lchunk = it * 256 + t;
                int row = graph * NP + rowbase + (lchunk >> 4);
                int idx = row * 16 + colblk;
                uint4 u = ((const uint4*)P.bufX)[idx];
                u32 uu[4] = {u.x, u.y, u.z, u.w};
                float v[8];
                #pragma unroll
                for (int p = 0; p < 4; ++p) {
                    v[2 * p] = fmaxf(fmaf(bfLo(uu[p]), sm.bn.scL[c + 2 * p], sm.bn.shL[c + 2 * p]), 0.f);
                    v[2 * p + 1] = fmaxf(fmaf(bfHi(uu[p]), sm.bn.scL[c + 2 * p + 1], sm.bn.shL[c + 2 * p + 1]), 0.f);
                }
                float z0 = 0.f, z1 = 0.f;
                #pragma unroll
                for (int j = 0; j < 8; ++j) {
                    z0 += v[j] * P.Wpool[(c + j) * 2];
                    z1 += v[j] * P.Wpool[(c + j) * 2 + 1];
                }
                #pragma unroll
                for (int o2 = 8; o2; o2 >>= 1) { z0 += __shfl_xor(z0, o2); z1 += __shfl_xor(z1, o2); }
                z0 += P.bpool[0]; z1 += P.bpool[1];
                float m = fmaxf(z0, z1);
                float e0 = expf(z0 - m), e1 = expf(z1 - m);
                float inv = 1.f / (e0 + e1);
                float s0 = e0 * inv, s1 = e1 * inv;
                if ((t & 15) == 0) { P.sarr[row * 2] = s0; P.sarr[row * 2 + 1] = s1; }
                #pragma unroll
                for (int j = 0; j < 8; ++j) { pa0[j] += s0 * v[j]; pa1[j] += s1 * v[j]; }
            }
            #pragma unroll
            for (int j = 0; j < 8; ++j) {
                atomicAdd(&sm.bn.poolL[c + j], pa0[j]);
                atomicAdd(&sm.bn.poolL[128 + c + j], pa1[j]);
            }
            __syncthreads();
            if (t < 128) atomicAdd(&P.pool[(graph * 2 + 0) * H + t], sm.bn.poolL[t]);
            else atomicAdd(&P.pool[(graph * 2 + 1) * H + (t - 128)], sm.bn.poolL[t]);
            __syncthreads();
        }
    }
    gsync(bar); bar += 64;

    // ===== P11: edge stats (num, den) + graph stats (ss) =====
    if (b < 256) {
        __syncthreads();
        int g = b >> 2, q = b & 3;
        int gbeg = P.gbase[g], gend = P.gbase[g + 1];
        for (int i = t; i < NP; i += NTHR) sm.es.sl[i] = ((const float2*)P.sarr)[g * NP + i];
        __syncthreads();
        float an = 0.f, ad = 0.f;
        int cnt = gend - gbeg;
        int q0 = gbeg + (cnt * q) / 4, q1 = gbeg + (cnt * (q + 1)) / 4;
        for (int i = q0 + t; i < q1; i += NTHR) {
            int2 r = P.sorted[i];
            float w = __int_as_float(r.y);
            float2 ss = sm.es.sl[r.x & 511];
            float2 sd = sm.es.sl[(r.x >> 9) & 511];
            an += w * (ss.x * sd.x + ss.y * sd.y);
            ad += w * (ss.x * ss.x + ss.y * ss.y);
        }
        for (int o = 32; o; o >>= 1) { an += __shfl_down(an, o); ad += __shfl_down(ad, o); }
        if ((t & 63) == 0) { sm.es.ln[t >> 6] = an; sm.es.ld[t >> 6] = ad; }
        __syncthreads();
        if (t == 0) {
            atomicAdd(&P.num[g], sm.es.ln[0] + sm.es.ln[1] + sm.es.ln[2] + sm.es.ln[3]);
            atomicAdd(&P.den[g], sm.es.ld[0] + sm.es.ld[1] + sm.es.ld[2] + sm.es.ld[3]);
        }
        if (q == 0) {
            float p00 = 0.f, p01 = 0.f, p11 = 0.f;
            for (int i = t; i < NP; i += NTHR) {
                float2 sv = sm.es.sl[i];
                p00 += sv.x * sv.x;
                p01 += sv.x * sv.y;
                p11 += sv.y * sv.y;
            }
            for (int o = 32; o; o >>= 1) {
                p00 += __shfl_down(p00, o);
                p01 += __shfl_down(p01, o);
                p11 += __shfl_down(p11, o);
            }
            if ((t & 63) == 0) {
                int w2 = t >> 6;
                sm.es.tp[0][w2] = p00; sm.es.tp[1][w2] = p01; sm.es.tp[2][w2] = p11;
            }
            __syncthreads();
            if (t == 0) {
                P.gst[g] = sm.es.tp[0][0] + sm.es.tp[0][1] + sm.es.tp[0][2] + sm.es.tp[0][3];
                P.gst[NB + g] = sm.es.tp[1][0] + sm.es.tp[1][1] + sm.es.tp[1][2] + sm.es.tp[1][3];
                P.gst[2 * NB + g] = sm.es.tp[2][0] + sm.es.tp[2][1] + sm.es.tp[2][2] + sm.es.tp[2][3];
            }
        }
    }
    gsync(bar); bar += 64;

    // ===== P12: logits + losses =====
    if (b < 64) {
        __syncthreads();
        float v = P.pool[b * 256 + t];
        v = v > 0.f ? v : 0.f;
        float p0 = v * P.Wpost[t * 2], p1 = v * P.Wpost[t * 2 + 1];
        for (int o = 32; o; o >>= 1) { p0 += __shfl_down(p0, o); p1 += __shfl_down(p1, o); }
        if ((t & 63) == 0) { sm.lg.t0[t >> 6] = p0; sm.lg.t1[t >> 6] = p1; }
        __syncthreads();
        if (t == 0) {
            P.out[b * 2] = sm.lg.t0[0] + sm.lg.t0[1] + sm.lg.t0[2] + sm.lg.t0[3] + P.bpost[0];
            P.out[b * 2 + 1] = sm.lg.t1[0] + sm.lg.t1[1] + sm.lg.t1[2] + sm.lg.t1[3] + P.bpost[1];
        }
    } else if (b == 64 && t < 64) {
        float s00 = P.gst[t], s01 = P.gst[NB + t], s11 = P.gst[2 * NB + t];
        float mc = -(P.num[t] / P.den[t]);
        float nrm = sqrtf(s00 * s00 + 2.f * s01 * s01 + s11 * s11);
        const float a = 0.70710678118654752440f;
        float d00 = s00 / nrm - a, d01 = s01 / nrm, d11 = s11 / nrm - a;
        float ol = sqrtf(d00 * d00 + 2.f * d01 * d01 + d11 * d11);
        for (int o = 32; o; o >>= 1) { mc += __shfl_down(mc, o); ol += __shfl_down(ol, o); }
        if (t == 0) {
            P.out[NB * 2] = mc * (1.f / NB);
            P.out[NB * 2 + 1] = ol * (1.f / NB);
        }
    }
}

// ---------------- launch ----------------
extern "C" void kernel_launch(void* const* d_in, const int* in_sizes, int n_in,
                              void* d_out, int out_size, void* d_ws, size_t ws_size,
                              hipStream_t stream) {
    char* ws = (char*)d_ws;
    KParams hp;
    hp.nf     = (const float*)d_in[0];
    hp.src    = (const int*)d_in[1];
    hp.dst    = ((const int*)d_in[1]) + NE;
    hp.ew     = (const float*)d_in[2];
    hp.Wpre   = (const float*)d_in[4];
    hp.bpre   = (const float*)d_in[5];
    hp.W1rel  = (const float*)d_in[6];
    hp.b1rel  = (const float*)d_in[7];
    hp.W1root = (const float*)d_in[8];
    hp.g1     = (const float*)d_in[9];
    hp.be1    = (const float*)d_in[10];
    hp.W2rel  = (const float*)d_in[11];
    hp.b2rel  = (const float*)d_in[12];
    hp.W2root = (const float*)d_in[13];
    hp.g2     = (const float*)d_in[14];
    hp.be2    = (const float*)d_in[15];
    hp.Wpool  = (const float*)d_in[16];
    hp.bpool  = (const float*)d_in[17];
    hp.Wpost  = (const float*)d_in[18];
    hp.bpost  = (const float*)d_in[19];
    hp.bufX   = (u16*)(ws + OFF_X);
    hp.bufY   = (u16*)(ws + OFF_Y);
    hp.bufAgg = (u16*)(ws + OFF_AGG);
    hp.tmp    = (int2*)(ws + OFF_TMP);
    hp.sorted = (int2*)(ws + OFF_SORT);
    hp.offs   = (int*)(ws + OFF_OFFS);
    hp.histG  = (int*)(ws + OFF_HISTG);
    hp.startG = (int*)(ws + OFF_STARTG);
    hp.gbase  = (int*)(ws + OFF_GBASE);
    hp.WT1    = (u16*)(ws + OFF_WT1);
    hp.WT2    = (u16*)(ws + OFF_WT2);
    hp.sarr   = (float*)(ws + OFF_S);
    hp.gst    = (float*)(ws + OFF_GST);
    hp.num    = (float*)(ws + OFF_NUM);
    hp.den    = (float*)(ws + OFF_DEN);
    hp.bn1    = (float*)(ws + OFF_BN);
    hp.bn2    = (float*)(ws + OFF_BN + SZ_BNL);
    hp.pool   = (float*)(ws + OFF_POOL);
    hp.zeroP  = (u32*)(ws + OFF_ZERO);
    hp.bars   = (u32*)(ws + OFF_BARS);
    hp.out    = (float*)d_out;

    hipMemsetAsync(ws + OFF_BARS, 0, 4096, stream);
    k_mega<<<GRID, NTHR, 0, stream>>>(hp);
}

// Round 9
// 279.994 us; speedup vs baseline: 5.1301x; 5.1301x over previous
//
#include <hip/hip_runtime.h>

#define NN 32768      // total nodes
#define NP 512        // nodes per graph
#define NB 64         // graphs
#define NE 1048576    // edges
#define FIN 16
#define H 128
#define BN_EPS 1e-5f
#define EPB 4096      // edges per hist/scatterA block
#define NBLK (NE / EPB)   // 256
#define CAPH 8704     // max edges per half-graph
#define NSH 32        // BN shadow copies

typedef unsigned int u32;
typedef unsigned short u16;
typedef __attribute__((ext_vector_type(8))) short bf16x8;
typedef __attribute__((ext_vector_type(4))) float f32x4;

__device__ __forceinline__ u16 f2bf(float f) {
    u32 u = __float_as_uint(f);
    return (u16)((u + 0x7fffu + ((u >> 16) & 1u)) >> 16);
}
__device__ __forceinline__ float bfLo(u32 p) { return __uint_as_float(p << 16); }
__device__ __forceinline__ float bfHi(u32 p) { return __uint_as_float(p & 0xffff0000u); }

// ---------------- workspace layout (bytes) ----------------
static constexpr size_t SZ_HALF   = (size_t)NN * H * 2;            // 8 MiB (bf16 act)
static constexpr size_t OFF_X     = 0;
static constexpr size_t OFF_AGG   = OFF_X + SZ_HALF;               // agg bf16 (aliases tmp)
static constexpr size_t OFF_TMP   = OFF_AGG;                       // int2 tmp (8 MiB)
static constexpr size_t OFF_SORT  = OFF_AGG + SZ_HALF;             // NE int2 (8 MiB)
static constexpr size_t OFF_OFFS  = OFF_SORT + (size_t)NE * 8;     // NN+8 ints
static constexpr size_t OFF_HISTG = OFF_OFFS + ((size_t)NN + 128) * 4;
static constexpr size_t OFF_STARTG= OFF_HISTG + (size_t)NBLK * NB * 4;
static constexpr size_t OFF_GBASE = OFF_STARTG + (size_t)NBLK * NB * 4;  // 65 ints
static constexpr size_t OFF_WT1   = OFF_GBASE + 512;               // 128*256 bf16 = 64 KiB
static constexpr size_t OFF_WT2   = OFF_WT1 + (size_t)H * 2 * H * 2;
static constexpr size_t OFF_S     = OFF_WT2 + (size_t)H * 2 * H * 2;   // NN*2 f32
static constexpr size_t OFF_GST   = OFF_S + (size_t)NN * 2 * 4;    // 3*NB f32
// --- zeroed region (one memset) ---
static constexpr size_t OFF_ZERO  = OFF_GST + 1024;
static constexpr size_t OFF_NUM   = OFF_ZERO;                      // NB f32
static constexpr size_t OFF_DEN   = OFF_NUM + 256;                 // NB f32
static constexpr size_t OFF_BN    = OFF_DEN + 256;                 // 2 layers * NSH * 2 * H f32
static constexpr size_t SZ_BNL    = (size_t)NSH * 2 * H * 4;
static constexpr size_t OFF_POOL  = OFF_BN + 2 * SZ_BNL;           // NB*2*H f32
static constexpr size_t ZERO_BYTES= (OFF_POOL + (size_t)NB * 2 * H * 4) - OFF_ZERO;

// ---------------- kernels ----------------

// fused prologue: [0,2048) x0 = nf@W_pre+b_pre ; [2048,2304) WT prep ; [2304,2560) hist
__global__ __launch_bounds__(256) void k_prep(
        const float* __restrict__ nf, const float* __restrict__ Wp,
        const float* __restrict__ bp,
        const float* __restrict__ W1_rel, const float* __restrict__ W1_root,
        const float* __restrict__ W2_rel, const float* __restrict__ W2_root,
        const int* __restrict__ src,
        u16* __restrict__ x0, u16* __restrict__ WT1, u16* __restrict__ WT2,
        int* __restrict__ histG) {
    int t = threadIdx.x, bid = blockIdx.x;
    if (bid < 2048) {                       // ---- pre: 16 nodes per block
        __shared__ float sW[FIN * H];
        __shared__ float sNF[16 * FIN];
        for (int i = t; i < FIN * H; i += 256) sW[i] = Wp[i];
        int n0 = bid * 16;
        sNF[t] = nf[n0 * FIN + t];
        __syncthreads();
        int col = t & 127, half = t >> 7;
        float b = bp[col];
        #pragma unroll
        for (int r = 0; r < 8; ++r) {
            int rr = half * 8 + r;
            float acc = b;
            #pragma unroll
            for (int f = 0; f < FIN; ++f) acc += sNF[rr * FIN + f] * sW[f * H + col];
            x0[(size_t)(n0 + rr) * H + col] = f2bf(acc);
        }
    } else if (bid < 2304) {                // ---- WT[c][k] = stacked W^T -> bf16
        int base = bid - 2048;
        const float* __restrict__ Wrel = (base < 128) ? W1_rel : W2_rel;
        const float* __restrict__ Wroot = (base < 128) ? W1_root : W2_root;
        u16* WT = (base < 128) ? WT1 : WT2;
        int i = (base & 127) * 256 + t;
        int c = i >> 8, k = i & 255;
        float v = (k < H) ? Wrel[k * H + c] : Wroot[(k - H) * H + c];
        WT[c * 256 + k] = f2bf(v);
    } else {                                // ---- per-chunk graph histogram
        __shared__ int h[NB];
        if (t < NB) h[t] = 0;
        __syncthreads();
        int ebase = (bid - 2304) * EPB;
        #pragma unroll
        for (int i = 0; i < EPB / 256; ++i) {
            int s = src[ebase + i * 256 + t];
            atomicAdd(&h[s >> 9], 1);
        }
        __syncthreads();
        if (t < NB) histG[(bid - 2304) * NB + t] = h[t];
    }
}

// scan histG -> per-(block,graph) global bases + per-graph bases. 1 block, 1024 threads.
__global__ __launch_bounds__(1024) void k_scanG(const int* __restrict__ histG,
                                                int* __restrict__ startG,
                                                int* __restrict__ gbase) {
    __shared__ int csum[16][64];
    __shared__ int gpre[64];
    int t = threadIdx.x;
    int g = t & 63, c = t >> 6;
    int vals[16];
    int s = 0;
    #pragma unroll
    for (int i = 0; i < 16; ++i) {
        vals[i] = histG[(c * 16 + i) * NB + g];
        s += vals[i];
    }
    csum[c][g] = s;
    __syncthreads();
    int pre = 0;
    for (int i = 0; i < c; ++i) pre += csum[i][g];
    if (c == 0) {
        int tot = 0;
        #pragma unroll
        for (int i = 0; i < 16; ++i) tot += csum[i][g];
        int x = tot;
        #pragma unroll
        for (int o = 1; o < 64; o <<= 1) {
            int y = __shfl_up(x, o);
            if (g >= o) x += y;
        }
        gpre[g] = x - tot;
        gbase[g] = x - tot;
        if (g == 63) gbase[64] = x;
    }
    __syncthreads();
    int run = gpre[g] + pre;
    #pragma unroll
    for (int i = 0; i < 16; ++i) {
        startG[(c * 16 + i) * NB + g] = run;
        run += vals[i];
    }
}

// LDS-staged graph-sort of each 4096-edge chunk -> coalesced writes.
__global__ __launch_bounds__(256) void k_scatterA(
        const int* __restrict__ src, const int* __restrict__ dst,
        const float* __restrict__ ew, const int* __restrict__ histG,
        const int* __restrict__ startG, int2* __restrict__ tmp) {
    __shared__ int lstart[NB + 1];
    __shared__ int cursor[NB];
    __shared__ int gdst[NB];
    __shared__ int2 buf[EPB];   // 32 KB
    int t = threadIdx.x, bid = blockIdx.x;
    if (t < NB) {
        int c = histG[bid * NB + t];
        int x = c;
        #pragma unroll
        for (int o = 1; o < 64; o <<= 1) {
            int y = __shfl_up(x, o);
            if (t >= o) x += y;
        }
        lstart[t] = x - c;
        cursor[t] = x - c;
        gdst[t] = startG[bid * NB + t];
        if (t == 63) lstart[NB] = x;
    }
    __syncthreads();
    int ebase = bid * EPB;
    #pragma unroll
    for (int i = 0; i < EPB / 256; ++i) {
        int e = ebase + i * 256 + t;
        int s = src[e], d = dst[e];
        float w = ew[e];
        int g = s >> 9;
        int meta = (s & 511) | ((d & 511) << 9);
        int p = atomicAdd(&cursor[g], 1);
        buf[p] = make_int2(meta, __float_as_int(w));
    }
    __syncthreads();
    // flat write-out: every lane stores every iter; 6-step LDS binary search for g(i)
    for (int i = t; i < EPB; i += 256) {
        int lo = 0;
        #pragma unroll
        for (int stp = 32; stp; stp >>= 1)
            if (lstart[lo + stp] <= i) lo += stp;
        tmp[gdst[lo] + (i - lstart[lo])] = buf[i];
    }
}

// per-graph counting sort by dst (2 blocks/graph). Emits final CSR + offs.
__global__ __launch_bounds__(512) void k_sortB(
        const int2* __restrict__ tmp, const int* __restrict__ gbase,
        int2* __restrict__ sorted, int* __restrict__ offs) {
    __shared__ int hist[NP];
    __shared__ int start[NP + 1];
    __shared__ int cursor[NP / 2];
    __shared__ int wsum[8];
    __shared__ int perm[CAPH];   // 34 KB
    int t = threadIdx.x;
    int lane = t & 63, wv = t >> 6;
    int g = blockIdx.x >> 1, half = blockIdx.x & 1;
    int gbeg = gbase[g], gend = gbase[g + 1];
    int cnt = gend - gbeg;
    hist[t] = 0;
    __syncthreads();
    for (int i = t; i < cnt; i += 512) {
        int meta = tmp[gbeg + i].x;
        atomicAdd(&hist[(meta >> 9) & 511], 1);
    }
    __syncthreads();
    int c = hist[t];
    int x = c;
    #pragma unroll
    for (int o = 1; o < 64; o <<= 1) {
        int y = __shfl_up(x, o);
        if (lane >= o) x += y;
    }
    if (lane == 63) wsum[wv] = x;
    __syncthreads();
    int off = 0;
    #pragma unroll
    for (int i = 0; i < 8; ++i) off += (i < wv) ? wsum[i] : 0;
    start[t] = off + x - c;           // exclusive prefix
    if (t == 511) start[NP] = off + x;
    __syncthreads();
    int h0 = half * 256;
    if (t < 256) {
        int n = h0 + t;
        offs[g * NP + n] = gbeg + start[n];
        cursor[t] = start[n];
    }
    if (blockIdx.x == 0 && t == 0) offs[NN] = NE;
    __syncthreads();
    int ha = start[h0];
    int hb = half ? cnt : start[256];
    for (int i = t; i < cnt; i += 512) {
        int meta = tmp[gbeg + i].x;
        int d = (meta >> 9) & 511;
        if ((d >> 8) == half) {
            int p = atomicAdd(&cursor[d - h0], 1);
            perm[p - ha] = i;
        }
    }
    __syncthreads();
    for (int o = ha + t; o < hb; o += 512) {
        sorted[gbeg + o] = tmp[gbeg + perm[o - ha]];
    }
}

// agg[node,:] = sum_e w_e * x[src_e,:]  (bf16 in/out, fp32 acc; 1 wave per node)
// 8-wide unroll, dual accumulator pairs for MLP/ILP.
__global__ __launch_bounds__(256) void k_agg(const u16* __restrict__ x,
        const int* __restrict__ offs, const int2* __restrict__ rec,
        u16* __restrict__ agg) {
    int wv = threadIdx.x >> 6, lane = threadIdx.x & 63;
    int b = blockIdx.x;
    int swz = (b & 7) * (NN / 8 / 4) + (b >> 3);   // XCD-locality swizzle
    int node = swz * 4 + wv;
    int sbase = node & ~(NP - 1);
    const u16* xg = x + (size_t)sbase * H;
    int beg = offs[node], end = offs[node + 1];
    float a0 = 0.f, a1 = 0.f, b0 = 0.f, b1 = 0.f;
    int j = beg;
    for (; j + 8 <= end; j += 8) {
        int2 r0 = rec[j], r1 = rec[j + 1], r2 = rec[j + 2], r3 = rec[j + 3];
        int2 r4 = rec[j + 4], r5 = rec[j + 5], r6 = rec[j + 6], r7 = rec[j + 7];
        u32 p0 = *(const u32*)(xg + (size_t)(r0.x & 511) * H + 2 * lane);
        u32 p1 = *(const u32*)(xg + (size_t)(r1.x & 511) * H + 2 * lane);
        u32 p2 = *(const u32*)(xg + (size_t)(r2.x & 511) * H + 2 * lane);
        u32 p3 = *(const u32*)(xg + (size_t)(r3.x & 511) * H + 2 * lane);
        u32 p4 = *(const u32*)(xg + (size_t)(r4.x & 511) * H + 2 * lane);
        u32 p5 = *(const u32*)(xg + (size_t)(r5.x & 511) * H + 2 * lane);
        u32 p6 = *(const u32*)(xg + (size_t)(r6.x & 511) * H + 2 * lane);
        u32 p7 = *(const u32*)(xg + (size_t)(r7.x & 511) * H + 2 * lane);
        float w0 = __int_as_float(r0.y), w1 = __int_as_float(r1.y);
        float w2 = __int_as_float(r2.y), w3 = __int_as_float(r3.y);
        float w4 = __int_as_float(r4.y), w5 = __int_as_float(r5.y);
        float w6 = __int_as_float(r6.y), w7 = __int_as_float(r7.y);
        a0 += w0 * bfLo(p0); a1 += w0 * bfHi(p0);
        b0 += w1 * bfLo(p1); b1 += w1 * bfHi(p1);
        a0 += w2 * bfLo(p2); a1 += w2 * bfHi(p2);
        b0 += w3 * bfLo(p3); b1 += w3 * bfHi(p3);
        a0 += w4 * bfLo(p4); a1 += w4 * bfHi(p4);
        b0 += w5 * bfLo(p5); b1 += w5 * bfHi(p5);
        a0 += w6 * bfLo(p6); a1 += w6 * bfHi(p6);
        b0 += w7 * bfLo(p7); b1 += w7 * bfHi(p7);
    }
    for (; j + 2 <= end; j += 2) {
        int2 r0 = rec[j], r1 = rec[j + 1];
        u32 p0 = *(const u32*)(xg + (size_t)(r0.x & 511) * H + 2 * lane);
        u32 p1 = *(const u32*)(xg + (size_t)(r1.x & 511) * H + 2 * lane);
        float w0 = __int_as_float(r0.y), w1 = __int_as_float(r1.y);
        a0 += w0 * bfLo(p0); a1 += w0 * bfHi(p0);
        b0 += w1 * bfLo(p1); b1 += w1 * bfHi(p1);
    }
    if (j < end) {
        int2 r = rec[j];
        u32 p = *(const u32*)(xg + (size_t)(r.x & 511) * H + 2 * lane);
        float w = __int_as_float(r.y);
        a0 += w * bfLo(p); a1 += w * bfHi(p);
    }
    a0 += b0; a1 += b1;
    u32 packed = (u32)f2bf(a0) | ((u32)f2bf(a1) << 16);
    *(u32*)(agg + (size_t)node * H + 2 * lane) = packed;
}

// Y = [Amat|Xmat](bf16) @ WT^T(bf16) + brel via MFMA, fp32 acc. Y may alias Xmat.
__global__ __launch_bounds__(256) void k_gemm(
        const u16* __restrict__ Amat, const u16* Xmat,
        const u16* __restrict__ WT, const float* __restrict__ brel,
        u16* Y, float* __restrict__ bn_base) {
    __shared__ u16 sWT[128][264];          // [col][k], +8 pad
    __shared__ float colS[128], colQ[128];
    int tid = threadIdx.x;
    int w = tid >> 6, lane = tid & 63;
    int lr = lane & 15, lg = lane >> 4;
    int row0 = blockIdx.x * 64;
    int myrow = row0 + w * 16 + lr;

    bf16x8 af[8];
    const u16* pa = Amat + (size_t)myrow * H + lg * 8;
    const u16* px = Xmat + (size_t)myrow * H + lg * 8;
    #pragma unroll
    for (int kt = 0; kt < 4; ++kt) af[kt] = *(const bf16x8*)(pa + kt * 32);
    #pragma unroll
    for (int kt = 0; kt < 4; ++kt) af[4 + kt] = *(const bf16x8*)(px + kt * 32);

    for (int i = tid; i < 128 * 32; i += 256) {
        int r = i >> 5, c = i & 31;
        *(uint4*)&sWT[r][c * 8] = *(const uint4*)(WT + r * 256 + c * 8);
    }
    if (tid < 128) { colS[tid] = 0.f; colQ[tid] = 0.f; }
    __syncthreads();

    f32x4 acc[8];
    #pragma unroll
    for (int nt = 0; nt < 8; ++nt) acc[nt] = (f32x4){0.f, 0.f, 0.f, 0.f};

    #pragma unroll
    for (int kt = 0; kt < 8; ++kt) {
        #pragma unroll
        for (int nt = 0; nt < 8; ++nt) {
            bf16x8 bf = *(const bf16x8*)&sWT[nt * 16 + lr][kt * 32 + lg * 8];
            acc[nt] = __builtin_amdgcn_mfma_f32_16x16x32_bf16(af[kt], bf, acc[nt], 0, 0, 0);
        }
    }

    float cs[8], cq[8];
    #pragma unroll
    for (int nt = 0; nt < 8; ++nt) {
        int col = nt * 16 + lr;
        float bias = brel[col];
        float s = 0.f, q = 0.f;
        #pragma unroll
        for (int j = 0; j < 4; ++j) {
            float v = acc[nt][j] + bias;
            int row = row0 + w * 16 + lg * 4 + j;
            Y[(size_t)row * H + col] = f2bf(v);
            s += v; q += v * v;
        }
        cs[nt] = s; cq[nt] = q;
    }
    #pragma unroll
    for (int nt = 0; nt < 8; ++nt) {
        cs[nt] += __shfl_xor(cs[nt], 16); cs[nt] += __shfl_xor(cs[nt], 32);
        cq[nt] += __shfl_xor(cq[nt], 16); cq[nt] += __shfl_xor(cq[nt], 32);
    }
    if (lg == 0) {
        #pragma unroll
        for (int nt = 0; nt < 8; ++nt) {
            atomicAdd(&colS[nt * 16 + lr], cs[nt]);
            atomicAdd(&colQ[nt * 16 + lr], cq[nt]);
        }
    }
    __syncthreads();
    if (tid < 128) {
        int sh = blockIdx.x & (NSH - 1);
        atomicAdd(&bn_base[(sh * 2 + 0) * H + tid], colS[tid]);
        atomicAdd(&bn_base[(sh * 2 + 1) * H + tid], colQ[tid]);
    }
}

// BN finalize (per-block redundant shadow reduce) + ReLU apply, in-place bf16.
__global__ __launch_bounds__(256) void k_bnrelu(u16* __restrict__ y,
        const float* __restrict__ bn_base, const float* __restrict__ g,
        const float* __restrict__ be) {
    __shared__ float scL[H], shL[H];
    int t = threadIdx.x;
    if (t < H) {
        float su = 0.f, sq = 0.f;
        #pragma unroll
        for (int sh = 0; sh < NSH; ++sh) {
            su += bn_base[(sh * 2 + 0) * H + t];
            sq += bn_base[(sh * 2 + 1) * H + t];
        }
        float mu = su * (1.f / NN);
        float var = sq * (1.f / NN) - mu * mu;
        float sc = rsqrtf(var + BN_EPS) * g[t];
        scL[t] = sc;
        shL[t] = be[t] - mu * sc;
    }
    __syncthreads();
    #pragma unroll
    for (int it = 0; it < 4; ++it) {
        int idx = blockIdx.x * 1024 + it * 256 + t;
        int c = (idx & 15) * 8;
        uint4 u = ((const uint4*)y)[idx];
        u32 uu[4] = {u.x, u.y, u.z, u.w};
        u32 ro[4];
        #pragma unroll
        for (int p = 0; p < 4; ++p) {
            float v0 = fmaxf(fmaf(bfLo(uu[p]), scL[c + 2 * p], shL[c + 2 * p]), 0.f);
            float v1 = fmaxf(fmaf(bfHi(uu[p]), scL[c + 2 * p + 1], shL[c + 2 * p + 1]), 0.f);
            ro[p] = (u32)f2bf(v0) | ((u32)f2bf(v1) << 16);
        }
        uint4 o; o.x = ro[0]; o.y = ro[1]; o.z = ro[2]; o.w = ro[3];
        ((uint4*)y)[idx] = o;
    }
}

// layer 2: BN finalize + ReLU + s = softmax(x@W_pool+b_pool) + pool partials.
// Block covers 64 consecutive rows (all within one graph; 8 blocks/graph).
__global__ __launch_bounds__(256) void k_bnrelu_s(u16* __restrict__ y,
        const float* __restrict__ bn_base, const float* __restrict__ g,
        const float* __restrict__ be, const float* __restrict__ Wp,
        const float* __restrict__ bp, float* __restrict__ s,
        float* __restrict__ pool) {
    __shared__ float scL[H], shL[H];
    __shared__ float poolL[256];
    int t = threadIdx.x;
    if (t < H) {
        float su = 0.f, sq = 0.f;
        #pragma unroll
        for (int sh = 0; sh < NSH; ++sh) {
            su += bn_base[(sh * 2 + 0) * H + t];
            sq += bn_base[(sh * 2 + 1) * H + t];
        }
        float mu = su * (1.f / NN);
        float var = sq * (1.f / NN) - mu * mu;
        float sc = rsqrtf(var + BN_EPS) * g[t];
        scL[t] = sc;
        shL[t] = be[t] - mu * sc;
    }
    poolL[t] = 0.f;
    __syncthreads();
    int graph = blockIdx.x >> 3;
    int c = (t & 15) * 8;
    float pa0[8], pa1[8];
    #pragma unroll
    for (int j = 0; j < 8; ++j) { pa0[j] = 0.f; pa1[j] = 0.f; }
    #pragma unroll
    for (int it = 0; it < 4; ++it) {
        int idx = blockIdx.x * 1024 + it * 256 + t;
        uint4 u = ((const uint4*)y)[idx];
        u32 uu[4] = {u.x, u.y, u.z, u.w};
        u32 ro[4];
        float v[8];
        #pragma unroll
        for (int p = 0; p < 4; ++p) {
            v[2 * p] = fmaxf(fmaf(bfLo(uu[p]), scL[c + 2 * p], shL[c + 2 * p]), 0.f);
            v[2 * p + 1] = fmaxf(fmaf(bfHi(uu[p]), scL[c + 2 * p + 1], shL[c + 2 * p + 1]), 0.f);
            ro[p] = (u32)f2bf(v[2 * p]) | ((u32)f2bf(v[2 * p + 1]) << 16);
        }
        uint4 o; o.x = ro[0]; o.y = ro[1]; o.z = ro[2]; o.w = ro[3];
        ((uint4*)y)[idx] = o;
        float z0 = 0.f, z1 = 0.f;
        #pragma unroll
        for (int j = 0; j < 8; ++j) {
            z0 += v[j] * Wp[(c + j) * 2];
            z1 += v[j] * Wp[(c + j) * 2 + 1];
        }
        #pragma unroll
        for (int o2 = 8; o2; o2 >>= 1) { z0 += __shfl_xor(z0, o2); z1 += __shfl_xor(z1, o2); }
        z0 += bp[0]; z1 += bp[1];
        float m = fmaxf(z0, z1);
        float e0 = expf(z0 - m), e1 = expf(z1 - m);
        float inv = 1.f / (e0 + e1);
        float s0 = e0 * inv, s1 = e1 * inv;
        int row = idx >> 4;
        if ((t & 15) == 0) { s[row * 2] = s0; s[row * 2 + 1] = s1; }
        #pragma unroll
        for (int j = 0; j < 8; ++j) { pa0[j] += s0 * v[j]; pa1[j] += s1 * v[j]; }
    }
    #pragma unroll
    for (int j = 0; j < 8; ++j) {
        atomicAdd(&poolL[c + j], pa0[j]);
        atomicAdd(&poolL[128 + c + j], pa1[j]);
    }
    __syncthreads();
    if (t < 128) atomicAdd(&pool[(graph * 2 + 0) * H + t], poolL[t]);
    else atomicAdd(&pool[(graph * 2 + 1) * H + (t - 128)], poolL[t]);
}

// edge stats (num, den) + fused per-graph node stats on q==0 blocks. Grid 256.
__global__ __launch_bounds__(256) void k_edge(
        const int2* __restrict__ sorted, const int* __restrict__ gbase,
        const float* __restrict__ s, float* __restrict__ num,
        float* __restrict__ den, float* __restrict__ gst) {
    __shared__ float2 sl[NP];
    __shared__ float ln[4], ld2[4];
    int t = threadIdx.x;
    int g = blockIdx.x >> 2, q = blockIdx.x & 3;
    int gbeg = gbase[g], gend = gbase[g + 1];
    for (int i = t; i < NP; i += 256) sl[i] = ((const float2*)s)[g * NP + i];
    __syncthreads();
    float an = 0.f, ad = 0.f;
    int cnt = gend - gbeg;
    int q0 = gbeg + (cnt * q) / 4, q1 = gbeg + (cnt * (q + 1)) / 4;
    for (int i = q0 + t; i < q1; i += 256) {
        int2 r = sorted[i];
        float w = __int_as_float(r.y);
        float2 ss = sl[r.x & 511];
        float2 sd = sl[(r.x >> 9) & 511];
        an += w * (ss.x * sd.x + ss.y * sd.y);
        ad += w * (ss.x * ss.x + ss.y * ss.y);
    }
    for (int o = 32; o; o >>= 1) { an += __shfl_down(an, o); ad += __shfl_down(ad, o); }
    if ((t & 63) == 0) { ln[t >> 6] = an; ld2[t >> 6] = ad; }
    __syncthreads();
    if (t == 0) {
        atomicAdd(&num[g], ln[0] + ln[1] + ln[2] + ln[3]);
        atomicAdd(&den[g], ld2[0] + ld2[1] + ld2[2] + ld2[3]);
    }
    if (q == 0) {
        float p00 = 0.f, p01 = 0.f, p11 = 0.f;
        for (int i = t; i < NP; i += 256) {
            float2 sv = sl[i];
            p00 += sv.x * sv.x;
            p01 += sv.x * sv.y;
            p11 += sv.y * sv.y;
        }
        for (int o = 32; o; o >>= 1) {
            p00 += __shfl_down(p00, o);
            p01 += __shfl_down(p01, o);
            p11 += __shfl_down(p11, o);
        }
        __shared__ float tp[3][4];
        if ((t & 63) == 0) {
            int w = t >> 6;
            tp[0][w] = p00; tp[1][w] = p01; tp[2][w] = p11;
        }
        __syncthreads();
        if (t == 0) {
            gst[g] = tp[0][0] + tp[0][1] + tp[0][2] + tp[0][3];
            gst[NB + g] = tp[1][0] + tp[1][1] + tp[1][2] + tp[1][3];
            gst[2 * NB + g] = tp[2][0] + tp[2][1] + tp[2][2] + tp[2][3];
        }
    }
}

// bid<64: logits for graph bid ; bid==64: losses
__global__ void k_logits_losses(const float* __restrict__ pool, const float* __restrict__ Wpost,
                                const float* __restrict__ bpost, const float* __restrict__ num,
                                const float* __restrict__ den, const float* __restrict__ gst,
                                float* __restrict__ out) {
    int t = threadIdx.x;
    if (blockIdx.x < 64) {
        int b = blockIdx.x;
        float v = pool[b * 256 + t];
        v = v > 0.f ? v : 0.f;
        float p0 = v * Wpost[t * 2], p1 = v * Wpost[t * 2 + 1];
        for (int o = 32; o; o >>= 1) { p0 += __shfl_down(p0, o); p1 += __shfl_down(p1, o); }
        __shared__ float t0[4], t1[4];
        if ((t & 63) == 0) { t0[t >> 6] = p0; t1[t >> 6] = p1; }
        __syncthreads();
        if (t == 0) {
            out[b * 2] = t0[0] + t0[1] + t0[2] + t0[3] + bpost[0];
            out[b * 2 + 1] = t1[0] + t1[1] + t1[2] + t1[3] + bpost[1];
        }
    } else if (t < 64) {
        float s00 = gst[t], s01 = gst[NB + t], s11 = gst[2 * NB + t];
        float mc = -(num[t] / den[t]);
        float nrm = sqrtf(s00 * s00 + 2.f * s01 * s01 + s11 * s11);
        const float a = 0.70710678118654752440f;
        float d00 = s00 / nrm - a, d01 = s01 / nrm, d11 = s11 / nrm - a;
        float ol = sqrtf(d00 * d00 + 2.f * d01 * d01 + d11 * d11);
        for (int o = 32; o; o >>= 1) { mc += __shfl_down(mc, o); ol += __shfl_down(ol, o); }
        if (t == 0) {
            out[NB * 2] = mc * (1.f / NB);
            out[NB * 2 + 1] = ol * (1.f / NB);
        }
    }
}

// ---------------- launch ----------------
extern "C" void kernel_launch(void* const* d_in, const int* in_sizes, int n_in,
                              void* d_out, int out_size, void* d_ws, size_t ws_size,
                              hipStream_t stream) {
    const float* nf     = (const float*)d_in[0];
    const int*   ei     = (const int*)d_in[1];
    const float* ew     = (const float*)d_in[2];
    const float* W_pre  = (const float*)d_in[4];
    const float* b_pre  = (const float*)d_in[5];
    const float* W1_rel = (const float*)d_in[6];
    const float* b1_rel = (const float*)d_in[7];
    const float* W1_root= (const float*)d_in[8];
    const float* g1     = (const float*)d_in[9];
    const float* be1    = (const float*)d_in[10];
    const float* W2_rel = (const float*)d_in[11];
    const float* b2_rel = (const float*)d_in[12];
    const float* W2_root= (const float*)d_in[13];
    const float* g2     = (const float*)d_in[14];
    const float* be2    = (const float*)d_in[15];
    const float* W_pool = (const float*)d_in[16];
    const float* b_pool = (const float*)d_in[17];
    const float* W_post = (const float*)d_in[18];
    const float* b_post = (const float*)d_in[19];

    char* ws = (char*)d_ws;
    u16*   bufX   = (u16*)(ws + OFF_X);
    u16*   bufAgg = (u16*)(ws + OFF_AGG);
    int2*  tmp    = (int2*)(ws + OFF_TMP);
    int2*  sorted = (int2*)(ws + OFF_SORT);
    int*   offs   = (int*)(ws + OFF_OFFS);
    int*   histG  = (int*)(ws + OFF_HISTG);
    int*   startG = (int*)(ws + OFF_STARTG);
    int*   gbase  = (int*)(ws + OFF_GBASE);
    u16*   WT1    = (u16*)(ws + OFF_WT1);
    u16*   WT2    = (u16*)(ws + OFF_WT2);
    float* sarr   = (float*)(ws + OFF_S);
    float* gst    = (float*)(ws + OFF_GST);
    float* numA   = (float*)(ws + OFF_NUM);
    float* denA   = (float*)(ws + OFF_DEN);
    float* bn     = (float*)(ws + OFF_BN);
    float* pool   = (float*)(ws + OFF_POOL);
    float* outF   = (float*)d_out;

    const int* srcA = ei;
    const int* dstA = ei + NE;
    float* bn1 = bn;
    float* bn2 = (float*)(ws + OFF_BN + SZ_BNL);

    hipMemsetAsync(ws + OFF_ZERO, 0, ZERO_BYTES, stream);

    k_prep<<<2560, 256, 0, stream>>>(nf, W_pre, b_pre, W1_rel, W1_root,
                                     W2_rel, W2_root, srcA, bufX, WT1, WT2, histG);
    k_scanG<<<1, 1024, 0, stream>>>(histG, startG, gbase);
    k_scatterA<<<NBLK, 256, 0, stream>>>(srcA, dstA, ew, histG, startG, tmp);
    k_sortB<<<2 * NB, 512, 0, stream>>>(tmp, gbase, sorted, offs);

    // layer 1
    k_agg<<<NN / 4, 256, 0, stream>>>(bufX, offs, sorted, bufAgg);
    k_gemm<<<NN / 64, 256, 0, stream>>>(bufAgg, bufX, WT1, b1_rel, bufX, bn1);
    k_bnrelu<<<512, 256, 0, stream>>>(bufX, bn1, g1, be1);

    // layer 2
    k_agg<<<NN / 4, 256, 0, stream>>>(bufX, offs, sorted, bufAgg);
    k_gemm<<<NN / 64, 256, 0, stream>>>(bufAgg, bufX, WT2, b2_rel, bufX, bn2);
    k_bnrelu_s<<<512, 256, 0, stream>>>(bufX, bn2, g2, be2, W_pool, b_pool, sarr, pool);

    // losses
    k_edge<<<256, 256, 0, stream>>>(sorted, gbase, sarr, numA, denA, gst);
    k_logits_losses<<<NB + 1, 256, 0, stream>>>(pool, W_post, b_post, numA, denA, gst, outF);
}